// Round 15
// baseline (401.367 us; speedup 1.0000x reference)
//
#include <hip/hip_runtime.h>
#include <hip/hip_cooperative_groups.h>
#include <math.h>

typedef unsigned short u16;
typedef __attribute__((ext_vector_type(8))) short bf16x8;
typedef __attribute__((ext_vector_type(4))) float f32x4;

#define NN 32768      // total nodes
#define EDGES 524288  // total edges
#define NB 64         // graphs
#define NPG 512       // nodes per graph
#define EPG 8192      // edges per graph (contiguous in src/dst)
#define KEEP 256      // kept per graph
#define D 512         // feature dim

__device__ __forceinline__ float b2f(u16 h){ return __uint_as_float(((unsigned)h)<<16); }
__device__ __forceinline__ u16 f2b(float f){
  unsigned u = __float_as_uint(f);
  unsigned r = u + 0x7FFFu + ((u>>16)&1u);   // RNE
  return (u16)(r>>16);
}

// async global->LDS, 16B per lane (dest must be wave-uniform base + lane*16)
__device__ __forceinline__ void gload16(const void* g, void* l){
  __builtin_amdgcn_global_load_lds((const __attribute__((address_space(1))) void*)g,
                                   (__attribute__((address_space(3))) void*)l, 16, 0, 0);
}

// ---- inline dtype flag: 1 if x is f32, 0 if bf16 (sample first 128 u16s) ----
__device__ __forceinline__ int flag_f32(const u16* __restrict__ xb, int tid){
  __shared__ int fl;
  if (tid < 64){
    u16 v0 = xb[tid*2], v1 = xb[tid*2+1];
    int c = ((((v0>>7)&0xFF) > 140) ? 1 : 0) + ((((v1>>7)&0xFF) > 140) ? 1 : 0);
    #pragma unroll
    for (int o=32; o>=1; o>>=1) c += __shfl_xor(c, o);
    if (tid == 0) fl = (c > 8) ? 1 : 0;
  }
  __syncthreads();
  return fl;
}

// ---------- fused preprocessing (grid-partitioned, 512 threads/block) ----------
__global__ __launch_bounds__(512) void prep_kernel(
    const int* __restrict__ src, const int* __restrict__ dst,
    float* __restrict__ no, float* __restrict__ ni,
    int* __restrict__ rowp, int* __restrict__ csr,
    const void* __restrict__ x,
    const void* b1, const void* b2, const void* sW1v, const void* sW2v,
    const void* sb1, const void* sb2,
    float* b1c, float* b2c, float* sW1c, float* sW2c, float* sbc,
    const void* __restrict__ W1, const void* __restrict__ W2,
    u16* __restrict__ W1Th, u16* __restrict__ W1Tl,
    u16* __restrict__ W2Th, u16* __restrict__ W2Tl,
    u16* __restrict__ Xh, u16* __restrict__ Xl)
{
  __shared__ int sh_i[5][NPG];
  __shared__ float tile[32][33];
  int b = blockIdx.x, t = threadIdx.x;

  if (b < NB){
    int* dego = sh_i[0]; int* degi = sh_i[1]; int* s = sh_i[2];
    int* start = sh_i[3]; int* cur = sh_i[4];
    int g = b, n = t;
    dego[n] = 0; degi[n] = 0; cur[n] = 0;
    __syncthreads();
    int ebase = g*EPG;
    #pragma unroll
    for (int i = 0; i < 16; i++){
      int e = ebase + n + i*512;
      atomicAdd(&dego[src[e] & (NPG-1)], 1);
      atomicAdd(&degi[dst[e] & (NPG-1)], 1);
    }
    __syncthreads();
    int di = degi[n];
    s[n] = di;
    __syncthreads();
    for (int off=1; off<NPG; off<<=1){
      int val = (n>=off) ? s[n-off] : 0;
      __syncthreads();
      s[n] += val;
      __syncthreads();
    }
    int excl = s[n] - di;
    start[n] = excl;
    int a = dego[n]; if (a<1) a=1;
    int bb = di;     if (bb<1) bb=1;
    int v = g*NPG + n;
    no[v] = (float)(1.0/sqrt((double)a));
    ni[v] = (float)(1.0/sqrt((double)bb));
    rowp[v] = ebase + excl;
    if (g == NB-1 && n == NPG-1) rowp[NN] = EDGES;
    __syncthreads();
    #pragma unroll
    for (int i = 0; i < 16; i++){
      int e = ebase + n + i*512;
      int dl = dst[e] & (NPG-1);
      int pos = atomicAdd(&cur[dl], 1);
      csr[ebase + start[dl] + pos] = src[e];
    }
  } else if (b == NB){
    int f = flag_f32((const u16*)x, t);
    #define CV(p,i) (f ? ((const float*)(p))[i] : b2f(((const u16*)(p))[i]))
    b1c[t]  = CV(b1, t);
    b2c[t]  = CV(b2, t);
    sW1c[t] = CV(sW1v, t);
    sW2c[t] = CV(sW2v, t);
    if (t==0){ sbc[0] = CV(sb1,0); sbc[1] = CV(sb2,0); }
    #undef CV
  } else if (b < NB + 1 + 512){
    int f = flag_f32((const u16*)x, t);
    int id = b - (NB+1);
    const void* W = (id >> 8) ? W2 : W1;
    u16* WTh = (id >> 8) ? W2Th : W1Th;
    u16* WTl = (id >> 8) ? W2Tl : W1Tl;
    int rem = id & 255;
    int bx = (rem & 15)*32, by = (rem >> 4)*32;
    int tx = t & 31, ty = t >> 5;   // ty 0..15
    #pragma unroll
    for (int i=0;i<2;i++){
      size_t idx = (size_t)(by+ty+i*16)*D + bx+tx;
      tile[ty+i*16][tx] = f ? ((const float*)W)[idx] : b2f(((const u16*)W)[idx]);
    }
    __syncthreads();
    #pragma unroll
    for (int i=0;i<2;i++){
      float v = tile[tx][ty+i*16];
      u16 h = f2b(v);
      size_t o = (size_t)(bx+ty+i*16)*D + by+tx;
      WTh[o] = h;
      WTl[o] = f2b(v - b2f(h));
    }
  } else {
    int f = flag_f32((const u16*)x, t);
    int nblk = gridDim.x - (NB+1+512);
    int bid  = b - (NB+1+512);
    size_t stride = (size_t)nblk*512*4;
    for (size_t i = ((size_t)bid*512 + t)*4; i < (size_t)NN*D; i += stride){
      float v0,v1,v2,v3;
      if (f){
        float4 fv = *(const float4*)((const float*)x + i);
        v0=fv.x; v1=fv.y; v2=fv.z; v3=fv.w;
      } else {
        ushort4 uv = *(const ushort4*)((const u16*)x + i);
        v0=b2f(uv.x); v1=b2f(uv.y); v2=b2f(uv.z); v3=b2f(uv.w);
      }
      ushort4 hh, hl;
      hh.x=f2b(v0); hl.x=f2b(v0-b2f(hh.x));
      hh.y=f2b(v1); hl.y=f2b(v1-b2f(hh.y));
      hh.z=f2b(v2); hl.z=f2b(v2-b2f(hh.z));
      hh.w=f2b(v3); hl.w=f2b(v3-b2f(hh.w));
      *(ushort4*)(Xh+i) = hh;
      *(ushort4*)(Xl+i) = hl;
    }
  }
}

// ---------------- GEMM: C = (A @ W) * rowscale; A,B pre-split bf16 hi/lo ----------------
// 256x256 tile, 8 waves (2M x 4N), BK=32, double-buffered LDS (128 KB).
// K-loop fully unrolled: compile-time buf index -> immediate LDS offsets.

__device__ __forceinline__ void gemm_tile256(int id, int& brow, int& bcol){
  int xcd = id & 7, k = id >> 3;           // k: 0..31
  brow = (xcd + 8*(k >> 1)) * 256;         // both bcol-blocks of a panel -> same XCD
  bcol = (k & 1) * 256;
}

__global__ __launch_bounds__(512, 2) void gemm256(
    const u16* __restrict__ Ahg, const u16* __restrict__ Alg,
    const u16* __restrict__ BTh, const u16* __restrict__ BTl,
    float* __restrict__ C, const float* __restrict__ rowscale)
{
  __shared__ alignas(16) u16 lds[2][4][8192];
  int t = threadIdx.x;
  int brow, bcol;
  gemm_tile256(blockIdx.x, brow, bcol);
  int wid = t>>6, lane = t&63;
  int wr = wid>>2, wc = wid&3;             // wave grid 2 x 4, wave owns 128x64
  int q = lane>>4, r = lane&15;
  f32x4 acc[8][4] = {};

  int c0 = wid*128 + lane, c1 = c0 + 64;
  int q0 = c0>>8, r0 = c0&255, q1 = c1>>8, r1 = c1&255;
  const u16* sA0h = Ahg + (size_t)(brow+r0)*D + q0*8;
  const u16* sA1h = Ahg + (size_t)(brow+r1)*D + q1*8;
  const u16* sA0l = Alg + (size_t)(brow+r0)*D + q0*8;
  const u16* sA1l = Alg + (size_t)(brow+r1)*D + q1*8;
  const u16* sB0h = BTh + (size_t)(bcol+r0)*D + q0*8;
  const u16* sB1h = BTh + (size_t)(bcol+r1)*D + q1*8;
  const u16* sB0l = BTl + (size_t)(bcol+r0)*D + q0*8;
  const u16* sB1l = BTl + (size_t)(bcol+r1)*D + q1*8;

  #define STAGEK(B, KT) { int ko = (KT)*32; \
    gload16(sA0h+ko, &lds[B][0][c0*8]); gload16(sA1h+ko, &lds[B][0][c1*8]); \
    gload16(sA0l+ko, &lds[B][1][c0*8]); gload16(sA1l+ko, &lds[B][1][c1*8]); \
    gload16(sB0h+ko, &lds[B][2][c0*8]); gload16(sB1h+ko, &lds[B][2][c1*8]); \
    gload16(sB0l+ko, &lds[B][3][c0*8]); gload16(sB1l+ko, &lds[B][3][c1*8]); }

  STAGEK(0, 0)
  asm volatile("s_waitcnt vmcnt(0)" ::: "memory");
  __syncthreads();
  #pragma unroll
  for (int kt=0; kt<16; kt++){
    const int cur = kt & 1;
    if (kt < 15) STAGEK(cur^1, kt+1)
    bf16x8 fbh[4], fbl[4];
    #pragma unroll
    for (int n=0;n<4;n++){
      fbh[n] = *(const bf16x8*)(&lds[cur][2][(q*256 + wc*64 + n*16 + r)*8]);
      fbl[n] = *(const bf16x8*)(&lds[cur][3][(q*256 + wc*64 + n*16 + r)*8]);
    }
    __builtin_amdgcn_s_setprio(1);
    #pragma unroll
    for (int m=0;m<8;m++){
      bf16x8 fah = *(const bf16x8*)(&lds[cur][0][(q*256 + wr*128 + m*16 + r)*8]);
      bf16x8 fal = *(const bf16x8*)(&lds[cur][1][(q*256 + wr*128 + m*16 + r)*8]);
      #pragma unroll
      for (int n=0;n<4;n++){
        acc[m][n] = __builtin_amdgcn_mfma_f32_16x16x32_bf16(fah, fbh[n], acc[m][n], 0,0,0);
        acc[m][n] = __builtin_amdgcn_mfma_f32_16x16x32_bf16(fah, fbl[n], acc[m][n], 0,0,0);
        acc[m][n] = __builtin_amdgcn_mfma_f32_16x16x32_bf16(fal, fbh[n], acc[m][n], 0,0,0);
      }
    }
    __builtin_amdgcn_s_setprio(0);
    asm volatile("s_waitcnt vmcnt(0)" ::: "memory");
    __syncthreads();
  }
  #undef STAGEK

  #pragma unroll
  for (int m=0;m<8;m++){
    int rowb = brow + wr*128 + m*16 + q*4;
    #pragma unroll
    for (int n=0;n<4;n++){
      int col = bcol + wc*64 + n*16 + r;
      #pragma unroll
      for (int g=0; g<4; g++){
        int row = rowb + g;
        C[(size_t)row*D + col] = acc[m][n][g] * rowscale[row];
      }
    }
  }
}

// -------- edge aggregation: relu( (sum_{u in N(v)} Y[u]) * ni[v] + b ) --------
// 4 nodes/block (512 threads), 128 threads/node. CSR row in lane registers,
// gather unrolled x8. XCD-pinned per graph.
// mode 0: write split bf16 hi/lo.  mode 1: write bf16 Hb + fused score dots.

__global__ __launch_bounds__(512) void agg_kernel(
    const float* __restrict__ Y, const int* __restrict__ rowp,
    const int* __restrict__ csr, const float* __restrict__ ni,
    const float* __restrict__ bias,
    u16* __restrict__ Hh, u16* __restrict__ Hl,
    const float* __restrict__ sW1, const float* __restrict__ sW2,
    float* __restrict__ t1, float* __restrict__ t2, int mode)
{
  int i = blockIdx.x;                       // 8192 blocks
  int xcd = i & 7, j = i >> 3;              // j: 0..1023
  int quarter = threadIdx.x >> 7;           // node within quad (0..3)
  int t = threadIdx.x & 127;                // float4 chunk
  int lane = threadIdx.x & 63;
  int v = (xcd + 8*(j >> 7))*NPG + ((j & 127)*4 + quarter);
  int rp0 = rowp[v], rp1 = rowp[v+1];
  const float4* Yv = (const float4*)Y;
  float4 a = {0.f,0.f,0.f,0.f};
  for (int eb = rp0; eb < rp1; eb += 64){
    int cnt = rp1 - eb; if (cnt > 64) cnt = 64;
    int idx = (lane < cnt) ? csr[eb + lane] : 0;
    int e = 0;
    for (; e+8 <= cnt; e += 8){
      int u0 = __shfl(idx, e),   u1 = __shfl(idx, e+1);
      int u2 = __shfl(idx, e+2), u3 = __shfl(idx, e+3);
      int u4 = __shfl(idx, e+4), u5 = __shfl(idx, e+5);
      int u6 = __shfl(idx, e+6), u7 = __shfl(idx, e+7);
      float4 y0 = Yv[(size_t)u0*128 + t];
      float4 y1 = Yv[(size_t)u1*128 + t];
      float4 y2 = Yv[(size_t)u2*128 + t];
      float4 y3 = Yv[(size_t)u3*128 + t];
      float4 y4 = Yv[(size_t)u4*128 + t];
      float4 y5 = Yv[(size_t)u5*128 + t];
      float4 y6 = Yv[(size_t)u6*128 + t];
      float4 y7 = Yv[(size_t)u7*128 + t];
      a.x += ((y0.x + y1.x) + (y2.x + y3.x)) + ((y4.x + y5.x) + (y6.x + y7.x));
      a.y += ((y0.y + y1.y) + (y2.y + y3.y)) + ((y4.y + y5.y) + (y6.y + y7.y));
      a.z += ((y0.z + y1.z) + (y2.z + y3.z)) + ((y4.z + y5.z) + (y6.z + y7.z));
      a.w += ((y0.w + y1.w) + (y2.w + y3.w)) + ((y4.w + y5.w) + (y6.w + y7.w));
    }
    for (; e+4 <= cnt; e += 4){
      int u0 = __shfl(idx, e),   u1 = __shfl(idx, e+1);
      int u2 = __shfl(idx, e+2), u3 = __shfl(idx, e+3);
      float4 y0 = Yv[(size_t)u0*128 + t];
      float4 y1 = Yv[(size_t)u1*128 + t];
      float4 y2 = Yv[(size_t)u2*128 + t];
      float4 y3 = Yv[(size_t)u3*128 + t];
      a.x += (y0.x + y1.x) + (y2.x + y3.x);
      a.y += (y0.y + y1.y) + (y2.y + y3.y);
      a.z += (y0.z + y1.z) + (y2.z + y3.z);
      a.w += (y0.w + y1.w) + (y2.w + y3.w);
    }
    for (; e < cnt; e++){
      int u = __shfl(idx, e);
      float4 y = Yv[(size_t)u*128 + t];
      a.x += y.x; a.y += y.y; a.z += y.z; a.w += y.w;
    }
  }
  float w = ni[v];
  float4 b4 = ((const float4*)bias)[t];
  float4 rr;
  rr.x = fmaxf(a.x*w + b4.x, 0.f);
  rr.y = fmaxf(a.y*w + b4.y, 0.f);
  rr.z = fmaxf(a.z*w + b4.z, 0.f);
  rr.w = fmaxf(a.w*w + b4.w, 0.f);

  if (mode == 0){
    ushort4 hh, hl;
    hh.x = f2b(rr.x); hl.x = f2b(rr.x - b2f(hh.x));
    hh.y = f2b(rr.y); hl.y = f2b(rr.y - b2f(hh.y));
    hh.z = f2b(rr.z); hl.z = f2b(rr.z - b2f(hh.z));
    hh.w = f2b(rr.w); hl.w = f2b(rr.w - b2f(hh.w));
    *(ushort4*)(Hh + (size_t)v*D + t*4) = hh;
    *(ushort4*)(Hl + (size_t)v*D + t*4) = hl;
  } else {
    ushort4 hb;
    hb.x = f2b(rr.x); hb.y = f2b(rr.y); hb.z = f2b(rr.z); hb.w = f2b(rr.w);
    *(ushort4*)(Hh + (size_t)v*D + t*4) = hb;   // Hh doubles as bf16 H here
    float4 w1 = ((const float4*)sW1)[t];
    float4 w2 = ((const float4*)sW2)[t];
    float p1 = rr.x*w1.x + rr.y*w1.y + rr.z*w1.z + rr.w*w1.w;
    float p2 = rr.x*w2.x + rr.y*w2.y + rr.z*w2.z + rr.w*w2.w;
    #pragma unroll
    for (int off=32; off>=1; off>>=1){
      p1 += __shfl_xor(p1, off);
      p2 += __shfl_xor(p2, off);
    }
    __shared__ float red1[8], red2[8];
    int wv = threadIdx.x>>6;
    if (lane==0){ red1[wv] = p1; red2[wv] = p2; }
    __syncthreads();
    if (t==0){
      t1[v] = red1[quarter*2] + red1[quarter*2+1];
      t2[v] = red2[quarter*2] + red2[quarter*2+1];
    }
  }
}

// -------- cooperative fused tail: score agg + stable top-K + readout + combine --------
// 512 blocks x 512 threads. Phase A (blocks 0-63): per-graph scores (f64) + bitonic
// sort -> perm/gate. grid.sync. Phase B (all 512): gated gather + pooled write +
// segment partials. grid.sync. Phase C (blocks 0-63): fold 8 partials -> g_out.

__global__ __launch_bounds__(512) void tail_kernel(
    const float* __restrict__ t1, const float* __restrict__ t2,
    const int* __restrict__ rowp, const int* __restrict__ csr,
    const float* __restrict__ no, const float* __restrict__ ni,
    const float* __restrict__ sbc, const u16* __restrict__ Hb,
    int* __restrict__ perm, float* __restrict__ gate,
    float* __restrict__ gmx, float* __restrict__ gsm,
    float* __restrict__ outp, float* __restrict__ outg)
{
  __shared__ unsigned long long key[NPG];
  __shared__ float scl[NPG];
  __shared__ float4 redmx[3*128], redsm[3*128];
  cooperative_groups::grid_group grid = cooperative_groups::this_grid();
  int b = blockIdx.x, n = threadIdx.x;

  // ---- Phase A: scores + top-K (blocks 0..63) ----
  if (b < NB){
    int g = b;
    int v = g*NPG + n;
    double a1 = 0.0, a2 = 0.0;
    int rp1 = rowp[v+1];
    for (int e=rowp[v]; e<rp1; e++){
      int u = csr[e];
      double w = (double)no[u];
      a1 += (double)t1[u]*w;
      a2 += (double)t2[u]*w;
    }
    double wi = (double)ni[v];
    double s1 = a1*wi + (double)sbc[0];
    double s2 = a2*wi + (double)sbc[1];
    float s = (float)(0.5*(s1+s2));
    scl[n] = s;
    unsigned u = __float_as_uint(s);
    u = (u & 0x80000000u) ? ~u : (u | 0x80000000u);  // order-preserving (ascending)
    unsigned kd = ~u;                                 // descending score
    key[n] = ((unsigned long long)kd<<32) | (unsigned)n;
    __syncthreads();
    for (int k=2; k<=NPG; k<<=1){
      for (int j=k>>1; j>0; j>>=1){
        int ixj = n ^ j;
        if (ixj > n){
          unsigned long long a = key[n], bb = key[ixj];
          bool up = ((n & k) == 0);
          if ((a > bb) == up){ key[n] = bb; key[ixj] = a; }
        }
        __syncthreads();
      }
    }
    if (n < KEEP){
      int idx = (int)(key[n] & 0xFFFFFFFFull);
      perm[g*KEEP + n] = g*NPG + idx;
      gate[g*KEEP + n] = tanhf(scl[idx]);
    }
  }
  grid.sync();

  // ---- Phase B: gather + pooled write + segment partials (all 512 blocks) ----
  {
    int g = b >> 3, seg = b & 7;
    int qtr = n >> 7, c = n & 127;
    float4 mx = {-INFINITY,-INFINITY,-INFINITY,-INFINITY};
    float4 sm = {0.f,0.f,0.f,0.f};
    int base = seg*32;
    for (int rI = base + qtr; rI < base + 32; rI += 4){
      int node = perm[g*KEEP + rI];
      float gt = gate[g*KEEP + rI];
      ushort4 hv = *(const ushort4*)(Hb + (size_t)node*D + c*4);
      float4 vv;
      vv.x = b2f(hv.x)*gt; vv.y = b2f(hv.y)*gt;
      vv.z = b2f(hv.z)*gt; vv.w = b2f(hv.w)*gt;
      ((float4*)(outp + (size_t)(g*KEEP + rI)*D))[c] = vv;
      mx.x = fmaxf(mx.x, vv.x); mx.y = fmaxf(mx.y, vv.y);
      mx.z = fmaxf(mx.z, vv.z); mx.w = fmaxf(mx.w, vv.w);
      sm.x += vv.x; sm.y += vv.y; sm.z += vv.z; sm.w += vv.w;
    }
    __syncthreads();   // key/scl reuse barrier (phase A LDS dead now)
    if (qtr > 0){ redmx[(qtr-1)*128 + c] = mx; redsm[(qtr-1)*128 + c] = sm; }
    __syncthreads();
    if (qtr == 0){
      #pragma unroll
      for (int qq=0; qq<3; qq++){
        float4 omx = redmx[qq*128 + c], osm = redsm[qq*128 + c];
        mx.x = fmaxf(mx.x, omx.x); mx.y = fmaxf(mx.y, omx.y);
        mx.z = fmaxf(mx.z, omx.z); mx.w = fmaxf(mx.w, omx.w);
        sm.x += osm.x; sm.y += osm.y; sm.z += osm.z; sm.w += osm.w;
      }
      ((float4*)(gmx + (size_t)b*512))[c] = mx;
      ((float4*)(gsm + (size_t)b*512))[c] = sm;
    }
  }
  grid.sync();

  // ---- Phase C: fold 8 segment partials (blocks 0..63) ----
  if (b < NB){
    int g = b, d = n;
    float mx = -INFINITY, sm = 0.f;
    #pragma unroll
    for (int s=0; s<8; s++){
      mx = fmaxf(mx, gmx[(size_t)(g*8+s)*512 + d]);
      sm += gsm[(size_t)(g*8+s)*512 + d];
    }
    outg[(size_t)g*1024 + d] = mx;
    outg[(size_t)g*1024 + 512 + d] = sm;
  }
}

// ---------------- launch ----------------

extern "C" void kernel_launch(void* const* d_in, const int* in_sizes, int n_in,
                              void* d_out, int out_size, void* d_ws, size_t ws_size,
                              hipStream_t stream)
{
  (void)in_sizes; (void)n_in; (void)out_size; (void)ws_size;
  const void* x   = d_in[0];
  const int* src  = (const int*)d_in[1];
  const int* dst  = (const int*)d_in[2];
  const void* W1  = d_in[3];
  const void* b1  = d_in[4];
  const void* W2  = d_in[5];
  const void* b2  = d_in[6];
  const void* sW1 = d_in[7];
  const void* sb1 = d_in[8];
  const void* sW2 = d_in[9];
  const void* sb2 = d_in[10];
  float* out = (float*)d_out;

  char* ws = (char*)d_ws;
  size_t off = 0;
  auto alloc = [&](size_t bytes){ void* p = ws + off; off += (bytes + 255) & ~(size_t)255; return p; };
  float* no     = (float*)alloc((size_t)NN*4);
  float* ni     = (float*)alloc((size_t)NN*4);
  int*   rowp   = (int*)  alloc((size_t)(NN+1)*4);
  float* t1     = (float*)alloc((size_t)NN*4);
  float* t2     = (float*)alloc((size_t)NN*4);
  int*   perm   = (int*)  alloc((size_t)NB*KEEP*4);
  float* gate   = (float*)alloc((size_t)NB*KEEP*4);
  float* b1c    = (float*)alloc((size_t)D*4);
  float* b2c    = (float*)alloc((size_t)D*4);
  float* sW1c   = (float*)alloc((size_t)D*4);
  float* sW2c   = (float*)alloc((size_t)D*4);
  float* sbc    = (float*)alloc(2*4);
  float* gmx    = (float*)alloc((size_t)512*512*4);
  float* gsm    = (float*)alloc((size_t)512*512*4);
  u16*   W1Th   = (u16*)  alloc((size_t)D*D*2);
  u16*   W1Tl   = (u16*)  alloc((size_t)D*D*2);
  u16*   W2Th   = (u16*)  alloc((size_t)D*D*2);
  u16*   W2Tl   = (u16*)  alloc((size_t)D*D*2);
  int*   csr    = (int*)  alloc((size_t)EDGES*4);
  u16*   Hh     = (u16*)  alloc((size_t)NN*D*2);
  u16*   Hl     = (u16*)  alloc((size_t)NN*D*2);
  float* Y      = (float*)alloc((size_t)NN*D*4);
  u16*   Xh     = (u16*)  alloc((size_t)NN*D*2);
  u16*   Xl     = (u16*)  alloc((size_t)NN*D*2);
  u16*   Hb     = Hh;   // bf16 h2 reuses Hh in agg mode 1

  prep_kernel<<<2048, 512, 0, stream>>>(src, dst, no, ni, rowp, csr, x,
                                        b1, b2, sW1, sW2, sb1, sb2,
                                        b1c, b2c, sW1c, sW2c, sbc,
                                        W1, W2, W1Th, W1Tl, W2Th, W2Tl, Xh, Xl);

  // conv1: Y = (x @ W1) * no ; h1 = relu(agg) -> split bf16 (Hh, Hl)
  gemm256<<<256, 512, 0, stream>>>(Xh, Xl, W1Th, W1Tl, Y, no);
  agg_kernel<<<NN/4, 512, 0, stream>>>(Y, rowp, csr, ni, b1c, Hh, Hl,
                                       nullptr, nullptr, nullptr, nullptr, 0);
  // conv2: Y = (h1 @ W2) * no ; h2 = relu(agg) -> bf16 Hb + fused score dots
  gemm256<<<256, 512, 0, stream>>>(Hh, Hl, W2Th, W2Tl, Y, no);
  agg_kernel<<<NN/4, 512, 0, stream>>>(Y, rowp, csr, ni, b2c, Hb, nullptr,
                                       sW1c, sW2c, t1, t2, 1);

  // fused tail (cooperative: needs grid-wide sync between phases)
  float* outg = out + (size_t)NB*KEEP*D;
  void* args[] = { (void*)&t1, (void*)&t2, (void*)&rowp, (void*)&csr,
                   (void*)&no, (void*)&ni, (void*)&sbc, (void*)&Hb,
                   (void*)&perm, (void*)&gate, (void*)&gmx, (void*)&gsm,
                   (void*)&out, (void*)&outg };
  hipLaunchCooperativeKernel((void*)tail_kernel, dim3(512), dim3(512), args, 0, stream);
}

// Round 16
// 281.133 us; speedup vs baseline: 1.4277x; 1.4277x over previous
//
#include <hip/hip_runtime.h>
#include <math.h>

typedef unsigned short u16;
typedef __attribute__((ext_vector_type(8))) short bf16x8;
typedef __attribute__((ext_vector_type(4))) float f32x4;

#define NN 32768      // total nodes
#define EDGES 524288  // total edges
#define NB 64         // graphs
#define NPG 512       // nodes per graph
#define EPG 8192      // edges per graph (contiguous in src/dst)
#define KEEP 256      // kept per graph
#define D 512         // feature dim

__device__ __forceinline__ float b2f(u16 h){ return __uint_as_float(((unsigned)h)<<16); }
__device__ __forceinline__ u16 f2b(float f){
  unsigned u = __float_as_uint(f);
  unsigned r = u + 0x7FFFu + ((u>>16)&1u);   // RNE
  return (u16)(r>>16);
}

// async global->LDS, 16B per lane (dest must be wave-uniform base + lane*16)
__device__ __forceinline__ void gload16(const void* g, void* l){
  __builtin_amdgcn_global_load_lds((const __attribute__((address_space(1))) void*)g,
                                   (__attribute__((address_space(3))) void*)l, 16, 0, 0);
}

// ---- inline dtype flag: 1 if x is f32, 0 if bf16 (sample first 128 u16s) ----
__device__ __forceinline__ int flag_f32(const u16* __restrict__ xb, int tid){
  __shared__ int fl;
  if (tid < 64){
    u16 v0 = xb[tid*2], v1 = xb[tid*2+1];
    int c = ((((v0>>7)&0xFF) > 140) ? 1 : 0) + ((((v1>>7)&0xFF) > 140) ? 1 : 0);
    #pragma unroll
    for (int o=32; o>=1; o>>=1) c += __shfl_xor(c, o);
    if (tid == 0) fl = (c > 8) ? 1 : 0;
  }
  __syncthreads();
  return fl;
}

// ---------- fused preprocessing (grid-partitioned, 512 threads/block) ----------
__global__ __launch_bounds__(512) void prep_kernel(
    const int* __restrict__ src, const int* __restrict__ dst,
    float* __restrict__ no, float* __restrict__ ni,
    int* __restrict__ rowp, int* __restrict__ csr,
    const void* __restrict__ x,
    const void* b1, const void* b2, const void* sW1v, const void* sW2v,
    const void* sb1, const void* sb2,
    float* b1c, float* b2c, float* sW1c, float* sW2c, float* sbc,
    const void* __restrict__ W1, const void* __restrict__ W2,
    u16* __restrict__ W1Th, u16* __restrict__ W1Tl,
    u16* __restrict__ W2Th, u16* __restrict__ W2Tl,
    u16* __restrict__ Xh, u16* __restrict__ Xl)
{
  __shared__ int sh_i[5][NPG];
  __shared__ float tile[32][33];
  int b = blockIdx.x, t = threadIdx.x;

  if (b < NB){
    int* dego = sh_i[0]; int* degi = sh_i[1]; int* s = sh_i[2];
    int* start = sh_i[3]; int* cur = sh_i[4];
    int g = b, n = t;
    dego[n] = 0; degi[n] = 0; cur[n] = 0;
    __syncthreads();
    int ebase = g*EPG;
    #pragma unroll
    for (int i = 0; i < 16; i++){
      int e = ebase + n + i*512;
      atomicAdd(&dego[src[e] & (NPG-1)], 1);
      atomicAdd(&degi[dst[e] & (NPG-1)], 1);
    }
    __syncthreads();
    int di = degi[n];
    s[n] = di;
    __syncthreads();
    for (int off=1; off<NPG; off<<=1){
      int val = (n>=off) ? s[n-off] : 0;
      __syncthreads();
      s[n] += val;
      __syncthreads();
    }
    int excl = s[n] - di;
    start[n] = excl;
    int a = dego[n]; if (a<1) a=1;
    int bb = di;     if (bb<1) bb=1;
    int v = g*NPG + n;
    no[v] = (float)(1.0/sqrt((double)a));
    ni[v] = (float)(1.0/sqrt((double)bb));
    rowp[v] = ebase + excl;
    if (g == NB-1 && n == NPG-1) rowp[NN] = EDGES;
    __syncthreads();
    #pragma unroll
    for (int i = 0; i < 16; i++){
      int e = ebase + n + i*512;
      int dl = dst[e] & (NPG-1);
      int pos = atomicAdd(&cur[dl], 1);
      csr[ebase + start[dl] + pos] = src[e];
    }
  } else if (b == NB){
    int f = flag_f32((const u16*)x, t);
    #define CV(p,i) (f ? ((const float*)(p))[i] : b2f(((const u16*)(p))[i]))
    b1c[t]  = CV(b1, t);
    b2c[t]  = CV(b2, t);
    sW1c[t] = CV(sW1v, t);
    sW2c[t] = CV(sW2v, t);
    if (t==0){ sbc[0] = CV(sb1,0); sbc[1] = CV(sb2,0); }
    #undef CV
  } else if (b < NB + 1 + 512){
    int f = flag_f32((const u16*)x, t);
    int id = b - (NB+1);
    const void* W = (id >> 8) ? W2 : W1;
    u16* WTh = (id >> 8) ? W2Th : W1Th;
    u16* WTl = (id >> 8) ? W2Tl : W1Tl;
    int rem = id & 255;
    int bx = (rem & 15)*32, by = (rem >> 4)*32;
    int tx = t & 31, ty = t >> 5;   // ty 0..15
    #pragma unroll
    for (int i=0;i<2;i++){
      size_t idx = (size_t)(by+ty+i*16)*D + bx+tx;
      tile[ty+i*16][tx] = f ? ((const float*)W)[idx] : b2f(((const u16*)W)[idx]);
    }
    __syncthreads();
    #pragma unroll
    for (int i=0;i<2;i++){
      float v = tile[tx][ty+i*16];
      u16 h = f2b(v);
      size_t o = (size_t)(bx+ty+i*16)*D + by+tx;
      WTh[o] = h;
      WTl[o] = f2b(v - b2f(h));
    }
  } else {
    int f = flag_f32((const u16*)x, t);
    int nblk = gridDim.x - (NB+1+512);
    int bid  = b - (NB+1+512);
    size_t stride = (size_t)nblk*512*4;
    for (size_t i = ((size_t)bid*512 + t)*4; i < (size_t)NN*D; i += stride){
      float v0,v1,v2,v3;
      if (f){
        float4 fv = *(const float4*)((const float*)x + i);
        v0=fv.x; v1=fv.y; v2=fv.z; v3=fv.w;
      } else {
        ushort4 uv = *(const ushort4*)((const u16*)x + i);
        v0=b2f(uv.x); v1=b2f(uv.y); v2=b2f(uv.z); v3=b2f(uv.w);
      }
      ushort4 hh, hl;
      hh.x=f2b(v0); hl.x=f2b(v0-b2f(hh.x));
      hh.y=f2b(v1); hl.y=f2b(v1-b2f(hh.y));
      hh.z=f2b(v2); hl.z=f2b(v2-b2f(hh.z));
      hh.w=f2b(v3); hl.w=f2b(v3-b2f(hh.w));
      *(ushort4*)(Xh+i) = hh;
      *(ushort4*)(Xl+i) = hl;
    }
  }
}

// ---------------- GEMM: C = (A @ W) * rowscale; A,B pre-split bf16 hi/lo ----------------
// 256x256 tile, 8 waves (2M x 4N), BK=32, double-buffered LDS (128 KB).
// K-loop fully unrolled: compile-time buf index -> immediate LDS offsets.

__device__ __forceinline__ void gemm_tile256(int id, int& brow, int& bcol){
  int xcd = id & 7, k = id >> 3;           // k: 0..31
  brow = (xcd + 8*(k >> 1)) * 256;         // both bcol-blocks of a panel -> same XCD
  bcol = (k & 1) * 256;
}

__global__ __launch_bounds__(512, 2) void gemm256(
    const u16* __restrict__ Ahg, const u16* __restrict__ Alg,
    const u16* __restrict__ BTh, const u16* __restrict__ BTl,
    float* __restrict__ C, const float* __restrict__ rowscale)
{
  __shared__ alignas(16) u16 lds[2][4][8192];
  int t = threadIdx.x;
  int brow, bcol;
  gemm_tile256(blockIdx.x, brow, bcol);
  int wid = t>>6, lane = t&63;
  int wr = wid>>2, wc = wid&3;             // wave grid 2 x 4, wave owns 128x64
  int q = lane>>4, r = lane&15;
  f32x4 acc[8][4] = {};

  int c0 = wid*128 + lane, c1 = c0 + 64;
  int q0 = c0>>8, r0 = c0&255, q1 = c1>>8, r1 = c1&255;
  const u16* sA0h = Ahg + (size_t)(brow+r0)*D + q0*8;
  const u16* sA1h = Ahg + (size_t)(brow+r1)*D + q1*8;
  const u16* sA0l = Alg + (size_t)(brow+r0)*D + q0*8;
  const u16* sA1l = Alg + (size_t)(brow+r1)*D + q1*8;
  const u16* sB0h = BTh + (size_t)(bcol+r0)*D + q0*8;
  const u16* sB1h = BTh + (size_t)(bcol+r1)*D + q1*8;
  const u16* sB0l = BTl + (size_t)(bcol+r0)*D + q0*8;
  const u16* sB1l = BTl + (size_t)(bcol+r1)*D + q1*8;

  #define STAGEK(B, KT) { int ko = (KT)*32; \
    gload16(sA0h+ko, &lds[B][0][c0*8]); gload16(sA1h+ko, &lds[B][0][c1*8]); \
    gload16(sA0l+ko, &lds[B][1][c0*8]); gload16(sA1l+ko, &lds[B][1][c1*8]); \
    gload16(sB0h+ko, &lds[B][2][c0*8]); gload16(sB1h+ko, &lds[B][2][c1*8]); \
    gload16(sB0l+ko, &lds[B][3][c0*8]); gload16(sB1l+ko, &lds[B][3][c1*8]); }

  STAGEK(0, 0)
  asm volatile("s_waitcnt vmcnt(0)" ::: "memory");
  __syncthreads();
  #pragma unroll
  for (int kt=0; kt<16; kt++){
    const int cur = kt & 1;
    if (kt < 15) STAGEK(cur^1, kt+1)
    bf16x8 fbh[4], fbl[4];
    #pragma unroll
    for (int n=0;n<4;n++){
      fbh[n] = *(const bf16x8*)(&lds[cur][2][(q*256 + wc*64 + n*16 + r)*8]);
      fbl[n] = *(const bf16x8*)(&lds[cur][3][(q*256 + wc*64 + n*16 + r)*8]);
    }
    __builtin_amdgcn_s_setprio(1);
    #pragma unroll
    for (int m=0;m<8;m++){
      bf16x8 fah = *(const bf16x8*)(&lds[cur][0][(q*256 + wr*128 + m*16 + r)*8]);
      bf16x8 fal = *(const bf16x8*)(&lds[cur][1][(q*256 + wr*128 + m*16 + r)*8]);
      #pragma unroll
      for (int n=0;n<4;n++){
        acc[m][n] = __builtin_amdgcn_mfma_f32_16x16x32_bf16(fah, fbh[n], acc[m][n], 0,0,0);
        acc[m][n] = __builtin_amdgcn_mfma_f32_16x16x32_bf16(fah, fbl[n], acc[m][n], 0,0,0);
        acc[m][n] = __builtin_amdgcn_mfma_f32_16x16x32_bf16(fal, fbh[n], acc[m][n], 0,0,0);
      }
    }
    __builtin_amdgcn_s_setprio(0);
    asm volatile("s_waitcnt vmcnt(0)" ::: "memory");
    __syncthreads();
  }
  #undef STAGEK

  #pragma unroll
  for (int m=0;m<8;m++){
    int rowb = brow + wr*128 + m*16 + q*4;
    #pragma unroll
    for (int n=0;n<4;n++){
      int col = bcol + wc*64 + n*16 + r;
      #pragma unroll
      for (int g=0; g<4; g++){
        int row = rowb + g;
        C[(size_t)row*D + col] = acc[m][n][g] * rowscale[row];
      }
    }
  }
}

// -------- edge aggregation: relu( (sum_{u in N(v)} Y[u]) * ni[v] + b ) --------
// 4 nodes/block (512 threads), 128 threads/node. CSR row in lane registers,
// gather unrolled x8. XCD-pinned per graph.
// mode 0: write split bf16 hi/lo.  mode 1: write bf16 Hb + fused score dots.

__global__ __launch_bounds__(512) void agg_kernel(
    const float* __restrict__ Y, const int* __restrict__ rowp,
    const int* __restrict__ csr, const float* __restrict__ ni,
    const float* __restrict__ bias,
    u16* __restrict__ Hh, u16* __restrict__ Hl,
    const float* __restrict__ sW1, const float* __restrict__ sW2,
    float* __restrict__ t1, float* __restrict__ t2, int mode)
{
  int i = blockIdx.x;                       // 8192 blocks
  int xcd = i & 7, j = i >> 3;              // j: 0..1023
  int quarter = threadIdx.x >> 7;           // node within quad (0..3)
  int t = threadIdx.x & 127;                // float4 chunk
  int lane = threadIdx.x & 63;
  int v = (xcd + 8*(j >> 7))*NPG + ((j & 127)*4 + quarter);
  int rp0 = rowp[v], rp1 = rowp[v+1];
  const float4* Yv = (const float4*)Y;
  float4 a = {0.f,0.f,0.f,0.f};
  for (int eb = rp0; eb < rp1; eb += 64){
    int cnt = rp1 - eb; if (cnt > 64) cnt = 64;
    int idx = (lane < cnt) ? csr[eb + lane] : 0;
    int e = 0;
    for (; e+8 <= cnt; e += 8){
      int u0 = __shfl(idx, e),   u1 = __shfl(idx, e+1);
      int u2 = __shfl(idx, e+2), u3 = __shfl(idx, e+3);
      int u4 = __shfl(idx, e+4), u5 = __shfl(idx, e+5);
      int u6 = __shfl(idx, e+6), u7 = __shfl(idx, e+7);
      float4 y0 = Yv[(size_t)u0*128 + t];
      float4 y1 = Yv[(size_t)u1*128 + t];
      float4 y2 = Yv[(size_t)u2*128 + t];
      float4 y3 = Yv[(size_t)u3*128 + t];
      float4 y4 = Yv[(size_t)u4*128 + t];
      float4 y5 = Yv[(size_t)u5*128 + t];
      float4 y6 = Yv[(size_t)u6*128 + t];
      float4 y7 = Yv[(size_t)u7*128 + t];
      a.x += ((y0.x + y1.x) + (y2.x + y3.x)) + ((y4.x + y5.x) + (y6.x + y7.x));
      a.y += ((y0.y + y1.y) + (y2.y + y3.y)) + ((y4.y + y5.y) + (y6.y + y7.y));
      a.z += ((y0.z + y1.z) + (y2.z + y3.z)) + ((y4.z + y5.z) + (y6.z + y7.z));
      a.w += ((y0.w + y1.w) + (y2.w + y3.w)) + ((y4.w + y5.w) + (y6.w + y7.w));
    }
    for (; e+4 <= cnt; e += 4){
      int u0 = __shfl(idx, e),   u1 = __shfl(idx, e+1);
      int u2 = __shfl(idx, e+2), u3 = __shfl(idx, e+3);
      float4 y0 = Yv[(size_t)u0*128 + t];
      float4 y1 = Yv[(size_t)u1*128 + t];
      float4 y2 = Yv[(size_t)u2*128 + t];
      float4 y3 = Yv[(size_t)u3*128 + t];
      a.x += (y0.x + y1.x) + (y2.x + y3.x);
      a.y += (y0.y + y1.y) + (y2.y + y3.y);
      a.z += (y0.z + y1.z) + (y2.z + y3.z);
      a.w += (y0.w + y1.w) + (y2.w + y3.w);
    }
    for (; e < cnt; e++){
      int u = __shfl(idx, e);
      float4 y = Yv[(size_t)u*128 + t];
      a.x += y.x; a.y += y.y; a.z += y.z; a.w += y.w;
    }
  }
  float w = ni[v];
  float4 b4 = ((const float4*)bias)[t];
  float4 rr;
  rr.x = fmaxf(a.x*w + b4.x, 0.f);
  rr.y = fmaxf(a.y*w + b4.y, 0.f);
  rr.z = fmaxf(a.z*w + b4.z, 0.f);
  rr.w = fmaxf(a.w*w + b4.w, 0.f);

  if (mode == 0){
    ushort4 hh, hl;
    hh.x = f2b(rr.x); hl.x = f2b(rr.x - b2f(hh.x));
    hh.y = f2b(rr.y); hl.y = f2b(rr.y - b2f(hh.y));
    hh.z = f2b(rr.z); hl.z = f2b(rr.z - b2f(hh.z));
    hh.w = f2b(rr.w); hl.w = f2b(rr.w - b2f(hh.w));
    *(ushort4*)(Hh + (size_t)v*D + t*4) = hh;
    *(ushort4*)(Hl + (size_t)v*D + t*4) = hl;
  } else {
    ushort4 hb;
    hb.x = f2b(rr.x); hb.y = f2b(rr.y); hb.z = f2b(rr.z); hb.w = f2b(rr.w);
    *(ushort4*)(Hh + (size_t)v*D + t*4) = hb;   // Hh doubles as bf16 H here
    float4 w1 = ((const float4*)sW1)[t];
    float4 w2 = ((const float4*)sW2)[t];
    float p1 = rr.x*w1.x + rr.y*w1.y + rr.z*w1.z + rr.w*w1.w;
    float p2 = rr.x*w2.x + rr.y*w2.y + rr.z*w2.z + rr.w*w2.w;
    #pragma unroll
    for (int off=32; off>=1; off>>=1){
      p1 += __shfl_xor(p1, off);
      p2 += __shfl_xor(p2, off);
    }
    __shared__ float red1[8], red2[8];
    int wv = threadIdx.x>>6;
    if (lane==0){ red1[wv] = p1; red2[wv] = p2; }
    __syncthreads();
    if (t==0){
      t1[v] = red1[quarter*2] + red1[quarter*2+1];
      t2[v] = red2[quarter*2] + red2[quarter*2+1];
    }
  }
}

// -------- score aggregation + stable top-K (per graph) --------

__global__ __launch_bounds__(512) void scoretopk_kernel(
    const float* __restrict__ t1, const float* __restrict__ t2,
    const int* __restrict__ rowp, const int* __restrict__ csr,
    const float* __restrict__ no, const float* __restrict__ ni,
    const float* __restrict__ sbc,
    int* __restrict__ perm, float* __restrict__ gate)
{
  __shared__ unsigned long long key[NPG];
  __shared__ float scl[NPG];
  int g = blockIdx.x, n = threadIdx.x;
  int v = g*NPG + n;
  double a1 = 0.0, a2 = 0.0;
  int rp1 = rowp[v+1];
  for (int e=rowp[v]; e<rp1; e++){
    int u = csr[e];
    double w = (double)no[u];
    a1 += (double)t1[u]*w;
    a2 += (double)t2[u]*w;
  }
  double wi = (double)ni[v];
  double s1 = a1*wi + (double)sbc[0];
  double s2 = a2*wi + (double)sbc[1];
  float s = (float)(0.5*(s1+s2));
  scl[n] = s;
  unsigned u = __float_as_uint(s);
  u = (u & 0x80000000u) ? ~u : (u | 0x80000000u);  // order-preserving (ascending)
  unsigned kd = ~u;                                 // descending score
  key[n] = ((unsigned long long)kd<<32) | (unsigned)n;
  __syncthreads();
  for (int k=2; k<=NPG; k<<=1){
    for (int j=k>>1; j>0; j>>=1){
      int ixj = n ^ j;
      if (ixj > n){
        unsigned long long a = key[n], b = key[ixj];
        bool up = ((n & k) == 0);
        if ((a > b) == up){ key[n] = b; key[ixj] = a; }
      }
      __syncthreads();
    }
  }
  if (n < KEEP){
    int idx = (int)(key[n] & 0xFFFFFFFFull);
    perm[g*KEEP + n] = g*NPG + idx;
    gate[g*KEEP + n] = tanhf(scl[idx]);
  }
}

// -------- gated gather + pooled write + partial max/sum (8 blocks per graph) --------

__global__ __launch_bounds__(256) void readout_kernel(const u16* __restrict__ Hb,
    const int* __restrict__ perm, const float* __restrict__ gate,
    float* __restrict__ outp, float* __restrict__ gmx, float* __restrict__ gsm)
{
  __shared__ float4 redmx[128], redsm[128];
  int b = blockIdx.x;          // 512 blocks: graph g = b>>3, rank segment seg = b&7
  int g = b >> 3, seg = b & 7;
  int t = threadIdx.x, half = t >> 7, c = t & 127;
  float4 mx = {-INFINITY,-INFINITY,-INFINITY,-INFINITY};
  float4 sm = {0.f,0.f,0.f,0.f};
  int base = seg*32;
  for (int rI = base + half; rI < base + 32; rI += 2){
    int node = perm[g*KEEP + rI];
    float gt = gate[g*KEEP + rI];
    ushort4 hv = *(const ushort4*)(Hb + (size_t)node*D + c*4);
    float4 vv;
    vv.x = b2f(hv.x)*gt; vv.y = b2f(hv.y)*gt;
    vv.z = b2f(hv.z)*gt; vv.w = b2f(hv.w)*gt;
    ((float4*)(outp + (size_t)(g*KEEP + rI)*D))[c] = vv;
    mx.x = fmaxf(mx.x, vv.x); mx.y = fmaxf(mx.y, vv.y);
    mx.z = fmaxf(mx.z, vv.z); mx.w = fmaxf(mx.w, vv.w);
    sm.x += vv.x; sm.y += vv.y; sm.z += vv.z; sm.w += vv.w;
  }
  if (half == 1){ redmx[c] = mx; redsm[c] = sm; }
  __syncthreads();
  if (half == 0){
    float4 omx = redmx[c], osm = redsm[c];
    mx.x = fmaxf(mx.x, omx.x); mx.y = fmaxf(mx.y, omx.y);
    mx.z = fmaxf(mx.z, omx.z); mx.w = fmaxf(mx.w, omx.w);
    sm.x += osm.x; sm.y += osm.y; sm.z += osm.z; sm.w += osm.w;
    ((float4*)(gmx + (size_t)b*512))[c] = mx;
    ((float4*)(gsm + (size_t)b*512))[c] = sm;
  }
}

// -------- fold 8 segment partials into g_out --------

__global__ __launch_bounds__(512) void combine_kernel(const float* __restrict__ gmx,
    const float* __restrict__ gsm, float* __restrict__ outg)
{
  int g = blockIdx.x, d = threadIdx.x;
  float mx = -INFINITY, sm = 0.f;
  #pragma unroll
  for (int s=0; s<8; s++){
    mx = fmaxf(mx, gmx[(size_t)(g*8+s)*512 + d]);
    sm += gsm[(size_t)(g*8+s)*512 + d];
  }
  outg[(size_t)g*1024 + d] = mx;
  outg[(size_t)g*1024 + 512 + d] = sm;
}

// ---------------- launch ----------------

extern "C" void kernel_launch(void* const* d_in, const int* in_sizes, int n_in,
                              void* d_out, int out_size, void* d_ws, size_t ws_size,
                              hipStream_t stream)
{
  (void)in_sizes; (void)n_in; (void)out_size; (void)ws_size;
  const void* x   = d_in[0];
  const int* src  = (const int*)d_in[1];
  const int* dst  = (const int*)d_in[2];
  const void* W1  = d_in[3];
  const void* b1  = d_in[4];
  const void* W2  = d_in[5];
  const void* b2  = d_in[6];
  const void* sW1 = d_in[7];
  const void* sb1 = d_in[8];
  const void* sW2 = d_in[9];
  const void* sb2 = d_in[10];
  float* out = (float*)d_out;

  char* ws = (char*)d_ws;
  size_t off = 0;
  auto alloc = [&](size_t bytes){ void* p = ws + off; off += (bytes + 255) & ~(size_t)255; return p; };
  float* no     = (float*)alloc((size_t)NN*4);
  float* ni     = (float*)alloc((size_t)NN*4);
  int*   rowp   = (int*)  alloc((size_t)(NN+1)*4);
  float* t1     = (float*)alloc((size_t)NN*4);
  float* t2     = (float*)alloc((size_t)NN*4);
  int*   perm   = (int*)  alloc((size_t)NB*KEEP*4);
  float* gate   = (float*)alloc((size_t)NB*KEEP*4);
  float* b1c    = (float*)alloc((size_t)D*4);
  float* b2c    = (float*)alloc((size_t)D*4);
  float* sW1c   = (float*)alloc((size_t)D*4);
  float* sW2c   = (float*)alloc((size_t)D*4);
  float* sbc    = (float*)alloc(2*4);
  float* gmx    = (float*)alloc((size_t)512*512*4);
  float* gsm    = (float*)alloc((size_t)512*512*4);
  u16*   W1Th   = (u16*)  alloc((size_t)D*D*2);
  u16*   W1Tl   = (u16*)  alloc((size_t)D*D*2);
  u16*   W2Th   = (u16*)  alloc((size_t)D*D*2);
  u16*   W2Tl   = (u16*)  alloc((size_t)D*D*2);
  int*   csr    = (int*)  alloc((size_t)EDGES*4);
  u16*   Hh     = (u16*)  alloc((size_t)NN*D*2);
  u16*   Hl     = (u16*)  alloc((size_t)NN*D*2);
  float* Y      = (float*)alloc((size_t)NN*D*4);
  u16*   Xh     = (u16*)  alloc((size_t)NN*D*2);
  u16*   Xl     = (u16*)  alloc((size_t)NN*D*2);
  u16*   Hb     = Hh;   // bf16 h2 reuses Hh in agg mode 1

  prep_kernel<<<2048, 512, 0, stream>>>(src, dst, no, ni, rowp, csr, x,
                                        b1, b2, sW1, sW2, sb1, sb2,
                                        b1c, b2c, sW1c, sW2c, sbc,
                                        W1, W2, W1Th, W1Tl, W2Th, W2Tl, Xh, Xl);

  // conv1: Y = (x @ W1) * no ; h1 = relu(agg) -> split bf16 (Hh, Hl)
  gemm256<<<256, 512, 0, stream>>>(Xh, Xl, W1Th, W1Tl, Y, no);
  agg_kernel<<<NN/4, 512, 0, stream>>>(Y, rowp, csr, ni, b1c, Hh, Hl,
                                       nullptr, nullptr, nullptr, nullptr, 0);
  // conv2: Y = (h1 @ W2) * no ; h2 = relu(agg) -> bf16 Hb + fused score dots
  gemm256<<<256, 512, 0, stream>>>(Hh, Hl, W2Th, W2Tl, Y, no);
  agg_kernel<<<NN/4, 512, 0, stream>>>(Y, rowp, csr, ni, b2c, Hb, nullptr,
                                       sW1c, sW2c, t1, t2, 1);

  scoretopk_kernel<<<NB, 512, 0, stream>>>(t1, t2, rowp, csr, no, ni, sbc, perm, gate);
  readout_kernel  <<<512, 256, 0, stream>>>(Hb, perm, gate, out, gmx, gsm);
  combine_kernel  <<<NB, 512, 0, stream>>>(gmx, gsm, out + (size_t)NB*KEEP*D);
}